// Round 8
// baseline (175.317 us; speedup 1.0000x reference)
//
#include <hip/hip_runtime.h>

// EulerRNNCell — Genois qubit SDE Euler-Maruyama rollout.
// B=512, NUM_TRAJ=64, 255 steps.
//
// R8 = R7 MEASUREMENT PROBE (resubmitted; R7 hit GPUAcquisitionTimeout).
// R3-R6 (four disjoint structures) all landed within the harness-fill noise
// band (102.9-113.8 us); model: dur_us = ~95-100 us fixed harness work
// (268 MB ws-poison fill ~41.5 us + input restore ~21 us + graph gaps) +
// a kernel never directly observed (top-5 cutoff ~41 us hides it).
// Probe: launch the (idempotent) rollout 4x in the same graph ->
// dur_probe - dur_R6 = 3 * t_rollout. Disambiguates "kernel ~10 us (at
// floor)" from "kernel ~35 us (still the target)".
//
// Output layout (floats): [0,3584) = out[512,7]; rho real plane [3584,5632);
// imag plane [5632,7680) if room.

#define BATCH   512
#define NTRAJ   64
#define NTOT    (BATCH * NTRAJ)   // 32768
#define TSTEPS  255

__device__ __forceinline__ void sde_step(float& x1, float& x2, float& x3,
                                         float w1, float w2, float omega)
{
    const float HG = 0.55f;                    // 0.5 * GAMMA
    const float K  = 0.44497190922573976f;     // sqrt(GAMMA*ETA/2)
    const float SD = 0.0625f;                  // sqrt(DT) = 2^-4 (exact)
    const float DT = 0.00390625f;              // 2^-8

    const float d1 = w1 * SD;
    const float d2 = w2 * SD;

    const float ax = -HG * x1;
    const float ay = -omega * x3 - HG * x2;
    const float az = omega * x2;

    const float bx = K * (-x1 * x3 * d1 + x2 * d2);
    const float by = K * (-x2 * x3 * d1 - x1 * d2);
    const float bz = K * ((1.0f - x3 * x3) * d1);

    const float y1 = x1 + DT * ax + bx;
    const float y2 = x2 + DT * ay + by;
    const float y3 = x3 + DT * az + bz;
    x1 = y1; x2 = y2; x3 = y3;
}

__device__ __forceinline__ void sde_step2(float& x1, float& x2, float& x3,
                                          float4 w, float omega)
{
    sde_step(x1, x2, x3, w.x, w.y, omega);
    sde_step(x1, x2, x3, w.z, w.w, omega);
}

// Kernel 1: one thread per trajectory, lanes on CONSECUTIVE trajectories.
__global__ __launch_bounds__(64) void euler_rollout_kernel(
    const float* __restrict__ inputs,   // [512,1]
    const float* __restrict__ bloch0,   // [3]
    const float* __restrict__ wvec,     // [32768, 255, 2]
    float* __restrict__ xs)             // ws: 3 planes of [32768]
{
    const int n = blockIdx.x * 64 + threadIdx.x;   // trajectory id
    const int b = n & (BATCH - 1);                 // n = r*512 + b, 512 pow2

    const float omega = inputs[b] + 1e-8f;

    float x1 = bloch0[0];
    float x2 = bloch0[1];
    float x3 = bloch0[2];

    // row of 255 float2 pairs; byte offset n*2040 -> 16B aligned iff n even
    const float2* __restrict__ wrow =
        reinterpret_cast<const float2*>(wvec) + (long long)n * TSTEPS;

    const int head = (n & 1);
    if (head) {
        const float2 wh = wrow[0];
        sde_step(x1, x2, x3, wh.x, wh.y, omega);
    }
    const float4* __restrict__ w4 =
        reinterpret_cast<const float4*>(wrow + head);

    // software pipeline: chunks of 4 float4 (8 steps), double-buffered A/B
    float4 a0, a1, a2, a3, c0, c1, c2, c3;
    a0 = w4[0]; a1 = w4[1]; a2 = w4[2]; a3 = w4[3];

    int k = 0;
#pragma unroll 1
    for (int it = 0; it < 15; ++it) {
        c0 = w4[k + 4]; c1 = w4[k + 5]; c2 = w4[k + 6]; c3 = w4[k + 7];
        sde_step2(x1, x2, x3, a0, omega);
        sde_step2(x1, x2, x3, a1, omega);
        sde_step2(x1, x2, x3, a2, omega);
        sde_step2(x1, x2, x3, a3, omega);
        a0 = w4[k + 8]; a1 = w4[k + 9]; a2 = w4[k + 10]; a3 = w4[k + 11];
        sde_step2(x1, x2, x3, c0, omega);
        sde_step2(x1, x2, x3, c1, omega);
        sde_step2(x1, x2, x3, c2, omega);
        sde_step2(x1, x2, x3, c3, omega);
        k += 8;
    }
    // k = 120: A holds float4 120..123; remainder 124..126
    sde_step2(x1, x2, x3, a0, omega);
    sde_step2(x1, x2, x3, a1, omega);
    sde_step2(x1, x2, x3, a2, omega);
    sde_step2(x1, x2, x3, a3, omega);
    c0 = w4[124]; c1 = w4[125]; c2 = w4[126];
    sde_step2(x1, x2, x3, c0, omega);
    sde_step2(x1, x2, x3, c1, omega);
    sde_step2(x1, x2, x3, c2, omega);
    if (!head) {
        const float2 wt = wrow[254];
        sde_step(x1, x2, x3, wt.x, wt.y, omega);
    }

    // SoA planes, coalesced (consecutive n per wave)
    xs[n]            = x1;
    xs[NTOT + n]     = x2;
    xs[2 * NTOT + n] = x3;
}

// Kernel 2: reduce 64 replicas per batch element + epilogue.
__global__ __launch_bounds__(64) void reduce_epilogue_kernel(
    const float* __restrict__ inputs,   // [512,1]
    const float* __restrict__ xs,       // ws: 3 planes of [32768]
    float* __restrict__ out,            // [out_size]
    int out_size)
{
    const int b = blockIdx.x * 64 + threadIdx.x;   // 8 blocks x 64 = 512

    float s1 = 0.0f, s2 = 0.0f, s3 = 0.0f;
#pragma unroll 8
    for (int r = 0; r < NTRAJ; ++r) {
        const int n = r * BATCH + b;               // lane-consecutive -> coalesced
        s1 += xs[n];
        s2 += xs[NTOT + n];
        s3 += xs[2 * NTOT + n];
    }

    const float inv = 1.0f / (float)NTRAJ;
    const float xm1 = s1 * inv;
    const float xm2 = s2 * inv;
    const float xm3 = s3 * inv;

    float px = 0.5f * (xm1 + 1.0f);
    float py = 0.5f * (xm2 + 1.0f);
    float pz = 0.5f * (xm3 + 1.0f);

    float p0 = fminf(fmaxf(px, 0.0f), 1.0f);
    float p1 = fminf(fmaxf(1.0f - px, 0.0f), 1.0f);
    float p2 = fminf(fmaxf(py, 0.0f), 1.0f);
    float p3 = fminf(fmaxf(1.0f - py, 0.0f), 1.0f);
    float p4 = fminf(fmaxf(pz, 0.0f), 1.0f);
    float p5 = fminf(fmaxf(1.0f - pz, 0.0f), 1.0f);

    float* o = out + (long long)b * 7;
    o[0] = p0; o[1] = p1; o[2] = p2; o[3] = p3; o[4] = p4; o[5] = p5;
    o[6] = inputs[b];

    // rho real parts: [(1+z)/2, x/2, x/2, (1-z)/2] at [3584, 5632)
    float* rre = out + BATCH * 7 + (long long)b * 4;
    rre[0] = (1.0f + xm3) * 0.5f;
    rre[1] = xm1 * 0.5f;
    rre[2] = xm1 * 0.5f;
    rre[3] = (1.0f - xm3) * 0.5f;

    // rho imag parts: [0, -y/2, y/2, 0] at [5632, 7680) if buffer has room
    if (out_size >= BATCH * 7 + BATCH * 8) {
        float* rim = out + BATCH * 7 + BATCH * 4 + (long long)b * 4;
        rim[0] = 0.0f;
        rim[1] = -xm2 * 0.5f;
        rim[2] = xm2 * 0.5f;
        rim[3] = 0.0f;
    }
}

extern "C" void kernel_launch(void* const* d_in, const int* in_sizes, int n_in,
                              void* d_out, int out_size, void* d_ws, size_t ws_size,
                              hipStream_t stream) {
    const float* inputs = (const float*)d_in[0];   // [512,1]
    const float* bloch0 = (const float*)d_in[1];   // [3]
    const float* wvec   = (const float*)d_in[2];   // [32768,255,2]
    float* out = (float*)d_out;
    float* xs  = (float*)d_ws;                     // 3*32768 floats = 393 KB

    // PROBE: 4x identical rollout launches (idempotent; same work every call).
    // dur_us here minus R6's dur_us ~= 3 * t_rollout.
    for (int rep = 0; rep < 4; ++rep) {
        euler_rollout_kernel<<<dim3(NTOT / 64), dim3(64), 0, stream>>>(
            inputs, bloch0, wvec, xs);
    }
    reduce_epilogue_kernel<<<dim3(BATCH / 64), dim3(64), 0, stream>>>(
        inputs, xs, out, out_size);
}

// Round 9
// 103.225 us; speedup vs baseline: 1.6984x; 1.6984x over previous
//
#include <hip/hip_runtime.h>

// EulerRNNCell — Genois qubit SDE Euler-Maruyama rollout.
// B=512 batch, NUM_TRAJ=64 trajectories/batch, T-1=255 steps.
// One block (1 wave, 64 threads) per batch element; thread j runs
// trajectory n = j*512 + b; mean over 64 trajectories = wave shuffle reduce.
//
// FINAL (R9 = revert to measured-best R3 config). R8's 4x-launch probe
// measured: fixed harness overhead ~91 us (268 MB ws-poison fill 41.5 us +
// input restore ~21 us + graph gaps, all inside the timed graph), R6-split
// rollout = 20.5 us, R3-fused ~= 12 us. The rollout reads 66.8 MB of noise
// exactly once -> streaming floor 10.6 us @ 6.3 TB/s; R3 is within ~1-2 us
// of it (below fill-jitter noise). Schedule variants (float4 R4, SW-pipeline
// R5, coalesced split R6) were all neutral-to-worse; keep the simplest.
//
// Output layout (floats): [0,3584) = out[512,7] (probs ++ inputs);
// rho real plane at [3584,5632); imag plane at [5632,7680) if room.

#define BATCH   512
#define NTRAJ   64
#define TSTEPS  255

__global__ __launch_bounds__(64) void euler_rollout_kernel(
    const float* __restrict__ inputs,   // [512,1]
    const float* __restrict__ bloch0,   // [3]
    const float* __restrict__ wvec,     // [32768, 255, 2]
    float* __restrict__ out,            // [out_size]
    int out_size)
{
    const int b = blockIdx.x;           // batch index
    const int j = threadIdx.x;          // trajectory replica 0..63
    const long long n = (long long)j * BATCH + b;

    const float omega = inputs[b] + 1e-8f;

    // constants, mirroring reference f32 values exactly
    const float HG = 0.55f;                       // 0.5 * GAMMA
    const float K  = 0.44497190922573976f;        // sqrt(GAMMA*ETA/2) = sqrt(0.198)
    const float SD = 0.0625f;                     // sqrt(DT) = 2^-4 (exact)
    const float DT = 0.00390625f;                 // 2^-8

    float x1 = bloch0[0];
    float x2 = bloch0[1];
    float x3 = bloch0[2];

    // row of 255 float2 noise pairs for this trajectory (8B aligned)
    const float2* __restrict__ wrow =
        reinterpret_cast<const float2*>(wvec) + n * TSTEPS;

    // Fully unrolled: all 255 loads are base+imm-offset, independent of the
    // x-chain, so the compiler hoists them deep ahead for latency hiding.
#pragma unroll
    for (int t = 0; t < TSTEPS; ++t) {
        const float2 w = wrow[t];
        const float d1 = w.x * SD;
        const float d2 = w.y * SD;

        const float ax = -HG * x1;
        const float ay = -omega * x3 - HG * x2;
        const float az = omega * x2;

        const float bx = K * (-x1 * x3 * d1 + x2 * d2);
        const float by = K * (-x2 * x3 * d1 - x1 * d2);
        const float bz = K * ((1.0f - x3 * x3) * d1);

        const float y1 = x1 + DT * ax + bx;
        const float y2 = x2 + DT * ay + by;
        const float y3 = x3 + DT * az + bz;
        x1 = y1; x2 = y2; x3 = y3;
    }

    // wave-wide sum over the 64 trajectories of this batch element
#pragma unroll
    for (int off = 32; off > 0; off >>= 1) {
        x1 += __shfl_xor(x1, off);
        x2 += __shfl_xor(x2, off);
        x3 += __shfl_xor(x3, off);
    }

    if (j == 0) {
        const float inv = 1.0f / (float)NTRAJ;
        const float xm1 = x1 * inv;
        const float xm2 = x2 * inv;
        const float xm3 = x3 * inv;

        float px = 0.5f * (xm1 + 1.0f);
        float py = 0.5f * (xm2 + 1.0f);
        float pz = 0.5f * (xm3 + 1.0f);

        float p0 = fminf(fmaxf(px, 0.0f), 1.0f);
        float p1 = fminf(fmaxf(1.0f - px, 0.0f), 1.0f);
        float p2 = fminf(fmaxf(py, 0.0f), 1.0f);
        float p3 = fminf(fmaxf(1.0f - py, 0.0f), 1.0f);
        float p4 = fminf(fmaxf(pz, 0.0f), 1.0f);
        float p5 = fminf(fmaxf(1.0f - pz, 0.0f), 1.0f);

        float* o = out + (long long)b * 7;
        o[0] = p0; o[1] = p1; o[2] = p2; o[3] = p3; o[4] = p4; o[5] = p5;
        o[6] = inputs[b];

        // rho real parts: [(1+z)/2, x/2, x/2, (1-z)/2] at [3584, 5632)
        float* rre = out + BATCH * 7 + (long long)b * 4;
        rre[0] = (1.0f + xm3) * 0.5f;
        rre[1] = xm1 * 0.5f;
        rre[2] = xm1 * 0.5f;
        rre[3] = (1.0f - xm3) * 0.5f;

        // rho imag parts: [0, -y/2, y/2, 0] at [5632, 7680) if buffer has room
        if (out_size >= BATCH * 7 + BATCH * 8) {
            float* rim = out + BATCH * 7 + BATCH * 4 + (long long)b * 4;
            rim[0] = 0.0f;
            rim[1] = -xm2 * 0.5f;
            rim[2] = xm2 * 0.5f;
            rim[3] = 0.0f;
        }
    }
}

extern "C" void kernel_launch(void* const* d_in, const int* in_sizes, int n_in,
                              void* d_out, int out_size, void* d_ws, size_t ws_size,
                              hipStream_t stream) {
    const float* inputs = (const float*)d_in[0];   // [512,1]
    const float* bloch0 = (const float*)d_in[1];   // [3]
    const float* wvec   = (const float*)d_in[2];   // [32768,255,2]
    float* out = (float*)d_out;

    euler_rollout_kernel<<<dim3(BATCH), dim3(64), 0, stream>>>(
        inputs, bloch0, wvec, out, out_size);
}